// Round 5
// baseline (1544.940 us; speedup 1.0000x reference)
//
#include <hip/hip_runtime.h>

#define NN 50000
#define NE 800000
#define DD 128
#define RR 8
#define MB (NN * RR)          // 400000 buckets keyed by (r, dst)
#define SCAN_BLK 2048
#define NBLK ((MB + SCAN_BLK - 1) / SCAN_BLK)   // 196

typedef __attribute__((ext_vector_type(8))) short short8;
typedef __attribute__((ext_vector_type(4))) float f32x4;

__device__ __forceinline__ unsigned short f2bf(float f)
{
    unsigned int u = __float_as_uint(f);
    u = (u + 0x7FFFu + ((u >> 16) & 1u)) >> 16;   // RNE
    return (unsigned short)u;
}
__device__ __forceinline__ float bflo(unsigned int p) { return __uint_as_float(p << 16); }
__device__ __forceinline__ float bfhi(unsigned int p) { return __uint_as_float(p & 0xFFFF0000u); }

// ---------------- count per (relation, dst) ----------------
__global__ __launch_bounds__(256) void k_count(const int* __restrict__ ei,
                                               const int* __restrict__ et,
                                               int* __restrict__ cnt)
{
    int e = blockIdx.x * 256 + threadIdx.x;
    if (e < NE) {
        int r = et[e];
        int dst = ei[NE + e];
        atomicAdd(&cnt[r * NN + dst], 1);
    }
}

// ---------------- exclusive scan over cnt -> off ----------------
__global__ __launch_bounds__(256) void k_scan1(const int* __restrict__ cnt,
                                               int* __restrict__ off,
                                               int* __restrict__ bsum)
{
    __shared__ int lds[256];
    int t = threadIdx.x;
    int base = blockIdx.x * SCAN_BLK + t * 8;
    int v[8], s = 0;
    #pragma unroll
    for (int j = 0; j < 8; j++) {
        int idx = base + j;
        v[j] = (idx < MB) ? cnt[idx] : 0;
        s += v[j];
    }
    lds[t] = s;
    __syncthreads();
    for (int d = 1; d < 256; d <<= 1) {
        int u = (t >= d) ? lds[t - d] : 0;
        __syncthreads();
        lds[t] += u;
        __syncthreads();
    }
    if (t == 255) bsum[blockIdx.x] = lds[255];
    int run = lds[t] - s;
    #pragma unroll
    for (int j = 0; j < 8; j++) {
        int idx = base + j;
        if (idx < MB) off[idx] = run;
        run += v[j];
    }
}

__global__ __launch_bounds__(256) void k_scan2(const int* __restrict__ bsum,
                                               int* __restrict__ carry)
{
    __shared__ int lds[256];
    int t = threadIdx.x;
    int s = (t < NBLK) ? bsum[t] : 0;
    lds[t] = s;
    __syncthreads();
    for (int d = 1; d < 256; d <<= 1) {
        int u = (t >= d) ? lds[t - d] : 0;
        __syncthreads();
        lds[t] += u;
        __syncthreads();
    }
    if (t < NBLK) carry[t] = lds[t] - s;
}

__global__ __launch_bounds__(256) void k_scan3(int* __restrict__ off,
                                               const int* __restrict__ carry)
{
    int c = carry[blockIdx.x];
    int base = blockIdx.x * SCAN_BLK + threadIdx.x * 8;
    #pragma unroll
    for (int j = 0; j < 8; j++) {
        int idx = base + j;
        if (idx < MB) off[idx] += c;
    }
    if (blockIdx.x == 0 && threadIdx.x == 0) off[MB] = NE;   // sentinel
}

// ---------------- place edges into CSR slots (src,dst pairs) ----------------
__global__ __launch_bounds__(256) void k_place(const int* __restrict__ ei,
                                               const int* __restrict__ et,
                                               const int* __restrict__ off,
                                               int* __restrict__ fill,
                                               int2* __restrict__ srt_pair)
{
    int e = blockIdx.x * 256 + threadIdx.x;
    if (e < NE) {
        int r = et[e];
        int src = ei[e];
        int dst = ei[NE + e];
        int b = r * NN + dst;
        int pos = off[b] + atomicAdd(&fill[b], 1);
        srt_pair[pos] = int2{src, dst};
    }
}

// ---------------- f32 -> bf16 convert (vectorized) ----------------
__global__ __launch_bounds__(256) void k_tobf16(const float* __restrict__ x,
                                                unsigned short* __restrict__ xb, int n4)
{
    int i = blockIdx.x * 256 + threadIdx.x;
    if (i < n4) {
        float4 v = ((const float4*)x)[i];
        uint2 o;
        o.x = (unsigned int)f2bf(v.x) | ((unsigned int)f2bf(v.y) << 16);
        o.y = (unsigned int)f2bf(v.z) | ((unsigned int)f2bf(v.w) << 16);
        ((uint2*)xb)[i] = o;
    }
}

// ---------------- weights: transpose + bf16: Wb[m][n][k] = src[m][k][n] ----------------
__global__ __launch_bounds__(256) void k_wconv(const float* __restrict__ W1,
                                               const float* __restrict__ root1,
                                               const float* __restrict__ W2,
                                               const float* __restrict__ root2,
                                               unsigned short* __restrict__ Wb)
{
    int e = blockIdx.x * 256 + threadIdx.x;
    if (e >= 18 * 16384) return;
    int m = e >> 14;
    int rem = e & 16383;
    int n = rem >> 7;
    int k = rem & 127;
    float v;
    if (m < 8)       v = W1[m * 16384 + k * 128 + n];
    else if (m == 8) v = root1[k * 128 + n];
    else if (m < 17) v = W2[(m - 9) * 16384 + k * 128 + n];
    else             v = root2[k * 128 + n];
    Wb[e] = f2bf(v);
}

// ---------------- fused layer, edge-parallel gather ----------------
// 64 dst-rows x 128 cols per block, 512 threads (8 waves).
// Wave w: rows ((w>>1)<<4)+0..15, cols (w&1)*64 + tt*16, tt=0..3.
__global__ __launch_bounds__(512) void k_layer(const unsigned short* __restrict__ Xin,
                                               const unsigned short* __restrict__ Wb,
                                               const float* __restrict__ bias,
                                               const int* __restrict__ off,
                                               const int* __restrict__ cnt,
                                               const int2* __restrict__ srt_pair,
                                               unsigned short* __restrict__ out_bf,
                                               float* __restrict__ out_f,
                                               int mode)
{
    __shared__ unsigned short Wl[128 * 128];   // 32 KB, XOR-swizzled [n][k]
    __shared__ float Aacc[64 * 128];           // 32 KB, XOR-swizzled f32 accumulator
    const int t = threadIdx.x;
    const int w = t >> 6;
    const int lane = t & 63;
    const int grow0 = blockIdx.x * 64;
    const int colb = lane & 15;
    const int hi = lane >> 4;
    const int g = t >> 4;        // 16-lane group id, 0..31
    const int l16 = t & 15;

    const int arow = ((w >> 1) << 4) + colb;   // A-tile row this lane reads for MFMA
    const int aswz = (arow & 7) << 4;

    f32x4 acc[4];
    #pragma unroll
    for (int tt = 0; tt < 4; tt++) acc[tt] = f32x4{0.f, 0.f, 0.f, 0.f};

    for (int m = 0; m < 9; m++) {
        // ---- phase A: stage W_m, zero Aacc (m<8) ----
        {
            const uint4* wsrc = (const uint4*)(Wb + (size_t)m * 16384);
            #pragma unroll
            for (int c = 0; c < 4; c++) {
                int u = c * 512 + t;           // 16B chunk id, 0..2047
                uint4 v = wsrc[u];
                int n = u >> 4;
                int dstb = (u * 16) ^ ((n & 7) << 4);
                *(uint4*)((char*)Wl + dstb) = v;
            }
        }
        if (m < 8) {
            #pragma unroll
            for (int i = 0; i < 8; i++) ((uint2*)Aacc)[t + 512 * i] = uint2{0u, 0u};
        }
        __syncthreads();

        // ---- phase B: edge-parallel accumulate into Aacc (m<8) ----
        if (m < 8) {
            int b0i = m * NN + grow0;
            int s0 = off[b0i];
            int lim = b0i + 64; int rel_end = (m + 1) * NN;
            int s1 = off[lim < rel_end ? lim : rel_end];
            for (int e = s0 + g; e < s1; e += 32) {
                int2 pr = srt_pair[e];
                int row = pr.y - grow0;
                const unsigned int* xr = (const unsigned int*)(Xin + (size_t)pr.x * 128);
                int sw = (row & 7) << 4;
                int rb = row * 512;
                #pragma unroll
                for (int j = 0; j < 4; j++) {
                    unsigned int u = xr[l16 + 16 * j];
                    int ad = (rb + (l16 * 8 + 128 * j)) ^ sw;
                    atomicAdd((float*)((char*)Aacc + ad), bflo(u));
                    atomicAdd((float*)((char*)Aacc + ad + 4), bfhi(u));
                }
            }
            __syncthreads();
        }

        // ---- phase C: MFMA ----
        if (m < 8) {
            int c = 1;
            if (grow0 + arow < NN) c = cnt[m * NN + grow0 + arow];
            float invc = 1.0f / (float)(c > 1 ? c : 1);
            #pragma unroll
            for (int ks = 0; ks < 4; ks++) {
                int e0 = arow * 512 + ks * 128 + hi * 32;
                f32x4 q0 = *(const f32x4*)((const char*)Aacc + (e0 ^ aswz));
                f32x4 q1 = *(const f32x4*)((const char*)Aacc + ((e0 + 16) ^ aswz));
                short8 af;
                #pragma unroll
                for (int j = 0; j < 4; j++) {
                    af[j]     = (short)f2bf(q0[j] * invc);
                    af[j + 4] = (short)f2bf(q1[j] * invc);
                }
                #pragma unroll
                for (int tt = 0; tt < 4; tt++) {
                    int n = (w & 1) * 64 + tt * 16 + colb;
                    int bbyte = (n * 256 + ks * 64 + hi * 16) ^ ((n & 7) << 4);
                    short8 bfr = *(const short8*)((const char*)Wl + bbyte);
                    acc[tt] = __builtin_amdgcn_mfma_f32_16x16x32_bf16(af, bfr, acc[tt], 0, 0, 0);
                }
            }
        } else {
            // root term: A-fragments straight from global Xin
            int rowg = grow0 + arow;
            #pragma unroll
            for (int ks = 0; ks < 4; ks++) {
                short8 af = short8{0,0,0,0,0,0,0,0};
                if (rowg < NN)
                    af = *(const short8*)(Xin + (size_t)rowg * 128 + ks * 32 + hi * 8);
                #pragma unroll
                for (int tt = 0; tt < 4; tt++) {
                    int n = (w & 1) * 64 + tt * 16 + colb;
                    int bbyte = (n * 256 + ks * 64 + hi * 16) ^ ((n & 7) << 4);
                    short8 bfr = *(const short8*)((const char*)Wl + bbyte);
                    acc[tt] = __builtin_amdgcn_mfma_f32_16x16x32_bf16(af, bfr, acc[tt], 0, 0, 0);
                }
            }
        }
        __syncthreads();
    }

    // ---- epilogue ----
    const int rl_base = (w >> 1) << 4;
    if (mode == 0) {
        #pragma unroll
        for (int tt = 0; tt < 4; tt++) {
            int col = (w & 1) * 64 + tt * 16 + colb;
            float bc = bias[col];
            #pragma unroll
            for (int j = 0; j < 4; j++) {
                int row = grow0 + rl_base + hi * 4 + j;
                if (row < NN) {
                    float v = fmaxf(acc[tt][j] + bc, 0.f);
                    out_bf[(size_t)row * 128 + col] = f2bf(v);
                }
            }
        }
    } else {
        float vv[4][4];
        float ss[4] = {0.f, 0.f, 0.f, 0.f};
        #pragma unroll
        for (int tt = 0; tt < 4; tt++) {
            int col = (w & 1) * 64 + tt * 16 + colb;
            float bc = bias[col];
            #pragma unroll
            for (int j = 0; j < 4; j++) {
                float v = acc[tt][j] + bc;
                vv[tt][j] = v;
                ss[j] += v * v;
            }
        }
        #pragma unroll
        for (int j = 0; j < 4; j++) {
            #pragma unroll
            for (int o = 1; o < 16; o <<= 1) ss[j] += __shfl_xor(ss[j], o);
        }
        // combine the two column-halves (wave pairs) via LDS scratch (alias Aacc)
        float* nrm = Aacc;   // [64][2]
        if (colb == 0) {
            #pragma unroll
            for (int j = 0; j < 4; j++) nrm[(rl_base + hi * 4 + j) * 2 + (w & 1)] = ss[j];
        }
        __syncthreads();
        #pragma unroll
        for (int tt = 0; tt < 4; tt++) {
            int col = (w & 1) * 64 + tt * 16 + colb;
            #pragma unroll
            for (int j = 0; j < 4; j++) {
                int rl = rl_base + hi * 4 + j;
                int row = grow0 + rl;
                if (row < NN) {
                    float tot = nrm[rl * 2] + nrm[rl * 2 + 1];
                    float inv = 1.0f / fmaxf(sqrtf(tot), 1e-12f);
                    out_f[(size_t)row * 128 + col] = vv[tt][j] * inv;
                }
            }
        }
    }
}

extern "C" void kernel_launch(void* const* d_in, const int* in_sizes, int n_in,
                              void* d_out, int out_size, void* d_ws, size_t ws_size,
                              hipStream_t stream)
{
    const float* x     = (const float*)d_in[0];
    const int*   ei    = (const int*)d_in[1];   // [2, E]
    const int*   et    = (const int*)d_in[2];   // [E]
    const float* W1    = (const float*)d_in[3];
    const float* root1 = (const float*)d_in[4];
    const float* b1    = (const float*)d_in[5];
    const float* W2    = (const float*)d_in[6];
    const float* root2 = (const float*)d_in[7];
    const float* b2    = (const float*)d_in[8];
    float* out = (float*)d_out;

    char* ws = (char*)d_ws;
    int* cnt   = (int*)ws;                       // MB
    int* fill  = cnt + MB;                       // MB (adjacent for one memset)
    int* off   = fill + MB;                      // MB+1
    int* bsum  = off + MB + 1;                   // 256
    int* carry = bsum + 256;                     // 256
    int2* srt  = (int2*)(carry + 256);           // NE pairs
    unsigned short* Xb = (unsigned short*)(srt + NE);       // NN*128
    unsigned short* hb = Xb + (size_t)NN * DD;              // NN*128
    unsigned short* Wb = hb + (size_t)NN * DD;              // 18*16384

    hipMemsetAsync(cnt, 0, (size_t)2 * MB * 4, stream);

    k_count<<<(NE + 255) / 256, 256, 0, stream>>>(ei, et, cnt);
    k_scan1<<<NBLK, 256, 0, stream>>>(cnt, off, bsum);
    k_scan2<<<1, 256, 0, stream>>>(bsum, carry);
    k_scan3<<<NBLK, 256, 0, stream>>>(off, carry);
    k_place<<<(NE + 255) / 256, 256, 0, stream>>>(ei, et, off, fill, srt);

    k_tobf16<<<(NN * DD / 4 + 255) / 256, 256, 0, stream>>>(x, Xb, NN * DD / 4);
    k_wconv<<<(18 * 16384 + 255) / 256, 256, 0, stream>>>(W1, root1, W2, root2, Wb);

    int lay_grid = (NN + 63) / 64;   // 782
    k_layer<<<lay_grid, 512, 0, stream>>>(Xb, Wb, b1, off, cnt, srt, hb, nullptr, 0);
    k_layer<<<lay_grid, 512, 0, stream>>>(hb, Wb + (size_t)9 * 16384, b2, off, cnt, srt, nullptr, out, 1);
}

// Round 6
// 379.173 us; speedup vs baseline: 4.0745x; 4.0745x over previous
//
#include <hip/hip_runtime.h>

#define NN 50000
#define NE 800000
#define DD 128
#define RR 8
#define MB (NN * RR)          // 400000 buckets keyed by (r, dst)
#define SCAN_BLK 2048
#define NBLK ((MB + SCAN_BLK - 1) / SCAN_BLK)   // 196

typedef __attribute__((ext_vector_type(8))) short short8;
typedef __attribute__((ext_vector_type(4))) float f32x4;

__device__ __forceinline__ unsigned short f2bf(float f)
{
    unsigned int u = __float_as_uint(f);
    u = (u + 0x7FFFu + ((u >> 16) & 1u)) >> 16;   // RNE
    return (unsigned short)u;
}
__device__ __forceinline__ float bflo(unsigned int p) { return __uint_as_float(p << 16); }
__device__ __forceinline__ float bfhi(unsigned int p) { return __uint_as_float(p & 0xFFFF0000u); }

// ---------------- count per (relation, dst) ----------------
__global__ __launch_bounds__(256) void k_count(const int* __restrict__ ei,
                                               const int* __restrict__ et,
                                               int* __restrict__ cnt)
{
    int e = blockIdx.x * 256 + threadIdx.x;
    if (e < NE) {
        int r = et[e];
        int dst = ei[NE + e];
        atomicAdd(&cnt[r * NN + dst], 1);
    }
}

// ---------------- exclusive scan over cnt -> off ----------------
__global__ __launch_bounds__(256) void k_scan1(const int* __restrict__ cnt,
                                               int* __restrict__ off,
                                               int* __restrict__ bsum)
{
    __shared__ int lds[256];
    int t = threadIdx.x;
    int base = blockIdx.x * SCAN_BLK + t * 8;
    int v[8], s = 0;
    #pragma unroll
    for (int j = 0; j < 8; j++) {
        int idx = base + j;
        v[j] = (idx < MB) ? cnt[idx] : 0;
        s += v[j];
    }
    lds[t] = s;
    __syncthreads();
    for (int d = 1; d < 256; d <<= 1) {
        int u = (t >= d) ? lds[t - d] : 0;
        __syncthreads();
        lds[t] += u;
        __syncthreads();
    }
    if (t == 255) bsum[blockIdx.x] = lds[255];
    int run = lds[t] - s;
    #pragma unroll
    for (int j = 0; j < 8; j++) {
        int idx = base + j;
        if (idx < MB) off[idx] = run;
        run += v[j];
    }
}

__global__ __launch_bounds__(256) void k_scan2(const int* __restrict__ bsum,
                                               int* __restrict__ carry)
{
    __shared__ int lds[256];
    int t = threadIdx.x;
    int s = (t < NBLK) ? bsum[t] : 0;
    lds[t] = s;
    __syncthreads();
    for (int d = 1; d < 256; d <<= 1) {
        int u = (t >= d) ? lds[t - d] : 0;
        __syncthreads();
        lds[t] += u;
        __syncthreads();
    }
    if (t < NBLK) carry[t] = lds[t] - s;
}

__global__ __launch_bounds__(256) void k_scan3(int* __restrict__ off,
                                               const int* __restrict__ carry)
{
    int c = carry[blockIdx.x];
    int base = blockIdx.x * SCAN_BLK + threadIdx.x * 8;
    #pragma unroll
    for (int j = 0; j < 8; j++) {
        int idx = base + j;
        if (idx < MB) off[idx] += c;
    }
    if (blockIdx.x == 0 && threadIdx.x == 0) off[MB] = NE;   // sentinel
}

// ---------------- place edges into CSR slots (src only; dst implied by slot) ----------------
__global__ __launch_bounds__(256) void k_place(const int* __restrict__ ei,
                                               const int* __restrict__ et,
                                               const int* __restrict__ off,
                                               int* __restrict__ fill,
                                               int* __restrict__ srt)
{
    int e = blockIdx.x * 256 + threadIdx.x;
    if (e < NE) {
        int r = et[e];
        int src = ei[e];
        int dst = ei[NE + e];
        int b = r * NN + dst;
        int pos = off[b] + atomicAdd(&fill[b], 1);
        srt[pos] = src;
    }
}

// ---------------- f32 -> bf16 convert (vectorized) ----------------
__global__ __launch_bounds__(256) void k_tobf16(const float* __restrict__ x,
                                                unsigned short* __restrict__ xb, int n4)
{
    int i = blockIdx.x * 256 + threadIdx.x;
    if (i < n4) {
        float4 v = ((const float4*)x)[i];
        uint2 o;
        o.x = (unsigned int)f2bf(v.x) | ((unsigned int)f2bf(v.y) << 16);
        o.y = (unsigned int)f2bf(v.z) | ((unsigned int)f2bf(v.w) << 16);
        ((uint2*)xb)[i] = o;
    }
}

// ---------------- weights: transpose + bf16: Wb[m][n][k] = src[m][k][n] ----------------
__global__ __launch_bounds__(256) void k_wconv(const float* __restrict__ W1,
                                               const float* __restrict__ root1,
                                               const float* __restrict__ W2,
                                               const float* __restrict__ root2,
                                               unsigned short* __restrict__ Wb)
{
    int e = blockIdx.x * 256 + threadIdx.x;
    if (e >= 18 * 16384) return;
    int m = e >> 14;
    int rem = e & 16383;
    int n = rem >> 7;
    int k = rem & 127;
    float v;
    if (m < 8)       v = W1[m * 16384 + k * 128 + n];
    else if (m == 8) v = root1[k * 128 + n];
    else if (m < 17) v = W2[(m - 9) * 16384 + k * 128 + n];
    else             v = root2[k * 128 + n];
    Wb[e] = f2bf(v);
}

// ---------------- fused layer: group-parallel gather, no atomics ----------------
// 64 dst-rows x 128 cols per block, 512 threads (8 waves, 32 x 16-lane groups).
// Group g owns rows 2g, 2g+1: register-accumulate its rows' edges, one ds_write_b128.
// MFMA: wave w does rows ((w>>1)<<4)+0..15, cols (w&1)*64 + tt*16.
__global__ __launch_bounds__(512) void k_layer(const unsigned short* __restrict__ Xin,
                                               const unsigned short* __restrict__ Wb,
                                               const float* __restrict__ bias,
                                               const int* __restrict__ off,
                                               const int* __restrict__ srt,
                                               unsigned short* __restrict__ out_bf,
                                               float* __restrict__ out_f,
                                               int mode)
{
    __shared__ unsigned short Wl[128 * 128];   // 32 KB, XOR-swizzled [n][k]
    __shared__ unsigned short Al[64 * 128];    // 16 KB, XOR-swizzled [row][k] bf16
    const int t = threadIdx.x;
    const int w = t >> 6;
    const int lane = t & 63;
    const int grow0 = blockIdx.x * 64;
    const int colb = lane & 15;
    const int hi = lane >> 4;
    const int g = t >> 4;        // 16-lane group id, 0..31
    const int l16 = t & 15;

    const int arow = ((w >> 1) << 4) + colb;   // A-tile row this lane reads for MFMA
    const int aswz = (arow & 7) << 4;

    f32x4 acc[4];
    #pragma unroll
    for (int tt = 0; tt < 4; tt++) acc[tt] = f32x4{0.f, 0.f, 0.f, 0.f};

    for (int m = 0; m < 9; m++) {
        // ---- stage W_m (transposed [n][k]) into Wl with swizzle ----
        {
            const uint4* wsrc = (const uint4*)(Wb + (size_t)m * 16384);
            #pragma unroll
            for (int c = 0; c < 4; c++) {
                int u = c * 512 + t;           // 16B chunk id, 0..2047
                uint4 v = wsrc[u];
                int n = u >> 4;
                int dstb = (u * 16) ^ ((n & 7) << 4);
                *(uint4*)((char*)Wl + dstb) = v;
            }
        }
        // ---- build A tile: group g accumulates rows 2g, 2g+1 in registers ----
        if (m < 8) {
            int b0 = m * NN + grow0;
            #pragma unroll
            for (int rr = 0; rr < 2; rr++) {
                int row = g * 2 + rr;
                int dstn = grow0 + row;
                float a0 = 0.f, a1 = 0.f, a2 = 0.f, a3 = 0.f;
                float a4 = 0.f, a5 = 0.f, a6 = 0.f, a7 = 0.f;
                int c = 0;
                if (dstn < NN) {
                    int s0 = off[b0 + row];
                    int s1 = off[b0 + row + 1];   // valid: next bucket start (sentinel at MB)
                    c = s1 - s0;
                    for (int k = 0; k < c; k++) {
                        int src = srt[s0 + k];
                        uint4 u = *(const uint4*)(Xin + (size_t)src * 128 + l16 * 8);
                        a0 += bflo(u.x); a1 += bfhi(u.x);
                        a2 += bflo(u.y); a3 += bfhi(u.y);
                        a4 += bflo(u.z); a5 += bfhi(u.z);
                        a6 += bflo(u.w); a7 += bfhi(u.w);
                    }
                }
                float invc = 1.0f / (float)(c > 1 ? c : 1);
                uint4 o;
                o.x = (unsigned int)f2bf(a0 * invc) | ((unsigned int)f2bf(a1 * invc) << 16);
                o.y = (unsigned int)f2bf(a2 * invc) | ((unsigned int)f2bf(a3 * invc) << 16);
                o.z = (unsigned int)f2bf(a4 * invc) | ((unsigned int)f2bf(a5 * invc) << 16);
                o.w = (unsigned int)f2bf(a6 * invc) | ((unsigned int)f2bf(a7 * invc) << 16);
                int byteoff = (row * 256 + l16 * 16) ^ ((row & 7) << 4);
                *(uint4*)((char*)Al + byteoff) = o;
            }
        }
        __syncthreads();

        // ---- MFMA ----
        if (m < 8) {
            #pragma unroll
            for (int ks = 0; ks < 4; ks++) {
                int abyte = (arow * 256 + ks * 64 + hi * 16) ^ aswz;
                short8 af = *(const short8*)((const char*)Al + abyte);
                #pragma unroll
                for (int tt = 0; tt < 4; tt++) {
                    int n = (w & 1) * 64 + tt * 16 + colb;
                    int bbyte = (n * 256 + ks * 64 + hi * 16) ^ ((n & 7) << 4);
                    short8 bfr = *(const short8*)((const char*)Wl + bbyte);
                    acc[tt] = __builtin_amdgcn_mfma_f32_16x16x32_bf16(af, bfr, acc[tt], 0, 0, 0);
                }
            }
        } else {
            // root term: A-fragments straight from global Xin
            int rowg = grow0 + arow;
            #pragma unroll
            for (int ks = 0; ks < 4; ks++) {
                short8 af = short8{0,0,0,0,0,0,0,0};
                if (rowg < NN)
                    af = *(const short8*)(Xin + (size_t)rowg * 128 + ks * 32 + hi * 8);
                #pragma unroll
                for (int tt = 0; tt < 4; tt++) {
                    int n = (w & 1) * 64 + tt * 16 + colb;
                    int bbyte = (n * 256 + ks * 64 + hi * 16) ^ ((n & 7) << 4);
                    short8 bfr = *(const short8*)((const char*)Wl + bbyte);
                    acc[tt] = __builtin_amdgcn_mfma_f32_16x16x32_bf16(af, bfr, acc[tt], 0, 0, 0);
                }
            }
        }
        __syncthreads();
    }

    // ---- epilogue ----
    const int rl_base = (w >> 1) << 4;
    if (mode == 0) {
        #pragma unroll
        for (int tt = 0; tt < 4; tt++) {
            int col = (w & 1) * 64 + tt * 16 + colb;
            float bc = bias[col];
            #pragma unroll
            for (int j = 0; j < 4; j++) {
                int row = grow0 + rl_base + hi * 4 + j;
                if (row < NN) {
                    float v = fmaxf(acc[tt][j] + bc, 0.f);
                    out_bf[(size_t)row * 128 + col] = f2bf(v);
                }
            }
        }
    } else {
        float vv[4][4];
        float ss[4] = {0.f, 0.f, 0.f, 0.f};
        #pragma unroll
        for (int tt = 0; tt < 4; tt++) {
            int col = (w & 1) * 64 + tt * 16 + colb;
            float bc = bias[col];
            #pragma unroll
            for (int j = 0; j < 4; j++) {
                float v = acc[tt][j] + bc;
                vv[tt][j] = v;
                ss[j] += v * v;
            }
        }
        #pragma unroll
        for (int j = 0; j < 4; j++) {
            #pragma unroll
            for (int o = 1; o < 16; o <<= 1) ss[j] += __shfl_xor(ss[j], o);
        }
        // combine the two column-halves (wave pairs) via LDS scratch (alias Al)
        float* nrm = (float*)Al;   // [64][2]
        if (colb == 0) {
            #pragma unroll
            for (int j = 0; j < 4; j++) nrm[(rl_base + hi * 4 + j) * 2 + (w & 1)] = ss[j];
        }
        __syncthreads();
        #pragma unroll
        for (int tt = 0; tt < 4; tt++) {
            int col = (w & 1) * 64 + tt * 16 + colb;
            #pragma unroll
            for (int j = 0; j < 4; j++) {
                int rl = rl_base + hi * 4 + j;
                int row = grow0 + rl;
                if (row < NN) {
                    float tot = nrm[rl * 2] + nrm[rl * 2 + 1];
                    float inv = 1.0f / fmaxf(sqrtf(tot), 1e-12f);
                    out_f[(size_t)row * 128 + col] = vv[tt][j] * inv;
                }
            }
        }
    }
}

extern "C" void kernel_launch(void* const* d_in, const int* in_sizes, int n_in,
                              void* d_out, int out_size, void* d_ws, size_t ws_size,
                              hipStream_t stream)
{
    const float* x     = (const float*)d_in[0];
    const int*   ei    = (const int*)d_in[1];   // [2, E]
    const int*   et    = (const int*)d_in[2];   // [E]
    const float* W1    = (const float*)d_in[3];
    const float* root1 = (const float*)d_in[4];
    const float* b1    = (const float*)d_in[5];
    const float* W2    = (const float*)d_in[6];
    const float* root2 = (const float*)d_in[7];
    const float* b2    = (const float*)d_in[8];
    float* out = (float*)d_out;

    char* ws = (char*)d_ws;
    int* cnt   = (int*)ws;                       // MB
    int* fill  = cnt + MB;                       // MB (adjacent for one memset)
    int* off   = fill + MB;                      // MB+1
    int* bsum  = off + MB + 1;                   // 256
    int* carry = bsum + 256;                     // 256
    int* srt   = carry + 256;                    // NE
    unsigned short* Xb = (unsigned short*)(srt + NE);       // NN*128
    unsigned short* hb = Xb + (size_t)NN * DD;              // NN*128
    unsigned short* Wb = hb + (size_t)NN * DD;              // 18*16384

    hipMemsetAsync(cnt, 0, (size_t)2 * MB * 4, stream);

    k_count<<<(NE + 255) / 256, 256, 0, stream>>>(ei, et, cnt);
    k_scan1<<<NBLK, 256, 0, stream>>>(cnt, off, bsum);
    k_scan2<<<1, 256, 0, stream>>>(bsum, carry);
    k_scan3<<<NBLK, 256, 0, stream>>>(off, carry);
    k_place<<<(NE + 255) / 256, 256, 0, stream>>>(ei, et, off, fill, srt);

    k_tobf16<<<(NN * DD / 4 + 255) / 256, 256, 0, stream>>>(x, Xb, NN * DD / 4);
    k_wconv<<<(18 * 16384 + 255) / 256, 256, 0, stream>>>(W1, root1, W2, root2, Wb);

    int lay_grid = (NN + 63) / 64;   // 782
    k_layer<<<lay_grid, 512, 0, stream>>>(Xb, Wb, b1, off, srt, hb, nullptr, 0);
    k_layer<<<lay_grid, 512, 0, stream>>>(hb, Wb + (size_t)9 * 16384, b2, off, srt, nullptr, out, 1);
}

// Round 7
// 322.440 us; speedup vs baseline: 4.7914x; 1.1759x over previous
//
#include <hip/hip_runtime.h>

#define NN 50000
#define NE 800000
#define DD 128
#define RR 8
#define MB (NN * RR)          // 400000 buckets keyed by (r, dst)
#define SCAN_BLK 2048
#define NBLK ((MB + SCAN_BLK - 1) / SCAN_BLK)   // 196

typedef __attribute__((ext_vector_type(8))) short short8;
typedef __attribute__((ext_vector_type(4))) float f32x4;

__device__ __forceinline__ unsigned short f2bf(float f)
{
    unsigned int u = __float_as_uint(f);
    u = (u + 0x7FFFu + ((u >> 16) & 1u)) >> 16;   // RNE
    return (unsigned short)u;
}
__device__ __forceinline__ float bflo(unsigned int p) { return __uint_as_float(p << 16); }
__device__ __forceinline__ float bfhi(unsigned int p) { return __uint_as_float(p & 0xFFFF0000u); }

// ---------------- count per (relation, dst) ----------------
__global__ __launch_bounds__(256) void k_count(const int* __restrict__ ei,
                                               const int* __restrict__ et,
                                               int* __restrict__ cnt)
{
    int e = blockIdx.x * 256 + threadIdx.x;
    if (e < NE) {
        int r = et[e];
        int dst = ei[NE + e];
        atomicAdd(&cnt[r * NN + dst], 1);
    }
}

// ---------------- exclusive scan over cnt -> off ----------------
__global__ __launch_bounds__(256) void k_scan1(const int* __restrict__ cnt,
                                               int* __restrict__ off,
                                               int* __restrict__ bsum)
{
    __shared__ int lds[256];
    int t = threadIdx.x;
    int base = blockIdx.x * SCAN_BLK + t * 8;
    int v[8], s = 0;
    #pragma unroll
    for (int j = 0; j < 8; j++) {
        int idx = base + j;
        v[j] = (idx < MB) ? cnt[idx] : 0;
        s += v[j];
    }
    lds[t] = s;
    __syncthreads();
    for (int d = 1; d < 256; d <<= 1) {
        int u = (t >= d) ? lds[t - d] : 0;
        __syncthreads();
        lds[t] += u;
        __syncthreads();
    }
    if (t == 255) bsum[blockIdx.x] = lds[255];
    int run = lds[t] - s;
    #pragma unroll
    for (int j = 0; j < 8; j++) {
        int idx = base + j;
        if (idx < MB) off[idx] = run;
        run += v[j];
    }
}

__global__ __launch_bounds__(256) void k_scan2(const int* __restrict__ bsum,
                                               int* __restrict__ carry)
{
    __shared__ int lds[256];
    int t = threadIdx.x;
    int s = (t < NBLK) ? bsum[t] : 0;
    lds[t] = s;
    __syncthreads();
    for (int d = 1; d < 256; d <<= 1) {
        int u = (t >= d) ? lds[t - d] : 0;
        __syncthreads();
        lds[t] += u;
        __syncthreads();
    }
    if (t < NBLK) carry[t] = lds[t] - s;
}

__global__ __launch_bounds__(256) void k_scan3(int* __restrict__ off,
                                               const int* __restrict__ carry)
{
    int c = carry[blockIdx.x];
    int base = blockIdx.x * SCAN_BLK + threadIdx.x * 8;
    #pragma unroll
    for (int j = 0; j < 8; j++) {
        int idx = base + j;
        if (idx < MB) off[idx] += c;
    }
    if (blockIdx.x == 0 && threadIdx.x == 0) off[MB] = NE;   // sentinel
}

// ---------------- place edges into CSR slots (src only) ----------------
__global__ __launch_bounds__(256) void k_place(const int* __restrict__ ei,
                                               const int* __restrict__ et,
                                               const int* __restrict__ off,
                                               int* __restrict__ fill,
                                               int* __restrict__ srt)
{
    int e = blockIdx.x * 256 + threadIdx.x;
    if (e < NE) {
        int r = et[e];
        int src = ei[e];
        int dst = ei[NE + e];
        int b = r * NN + dst;
        int pos = off[b] + atomicAdd(&fill[b], 1);
        srt[pos] = src;
    }
}

// ---------------- f32 -> bf16 convert (vectorized) ----------------
__global__ __launch_bounds__(256) void k_tobf16(const float* __restrict__ x,
                                                unsigned short* __restrict__ xb, int n4)
{
    int i = blockIdx.x * 256 + threadIdx.x;
    if (i < n4) {
        float4 v = ((const float4*)x)[i];
        uint2 o;
        o.x = (unsigned int)f2bf(v.x) | ((unsigned int)f2bf(v.y) << 16);
        o.y = (unsigned int)f2bf(v.z) | ((unsigned int)f2bf(v.w) << 16);
        ((uint2*)xb)[i] = o;
    }
}

// ---------------- weights: transpose + bf16: Wb[m][n][k] = src[m][k][n] ----------------
__global__ __launch_bounds__(256) void k_wconv(const float* __restrict__ W1,
                                               const float* __restrict__ root1,
                                               const float* __restrict__ W2,
                                               const float* __restrict__ root2,
                                               unsigned short* __restrict__ Wb)
{
    int e = blockIdx.x * 256 + threadIdx.x;
    if (e >= 18 * 16384) return;
    int m = e >> 14;
    int rem = e & 16383;
    int n = rem >> 7;
    int k = rem & 127;
    float v;
    if (m < 8)       v = W1[m * 16384 + k * 128 + n];
    else if (m == 8) v = root1[k * 128 + n];
    else if (m < 17) v = W2[(m - 9) * 16384 + k * 128 + n];
    else             v = root2[k * 128 + n];
    Wb[e] = f2bf(v);
}

// ---------------- fused layer: single-pass register gather + per-m MFMA ----------------
// 32 dst-rows x 128 cols per block, 512 threads (8 waves, 32 x 16-lane groups).
// Phase 1 (no barriers): group g accumulates row grow0+g for ALL 8 relations into
// 64 f32 regs (8 rel x 8 cols/lane). Phase 2 per m: ds_write A_m, stage W_m, MFMA.
// Wave w: row-tile rt=w&1, col-tiles (w>>1) and (w>>1)+4.
__global__ __launch_bounds__(512) void k_layer(const unsigned short* __restrict__ Xin,
                                               const unsigned short* __restrict__ Wb,
                                               const float* __restrict__ bias,
                                               const int* __restrict__ off,
                                               const int* __restrict__ srt,
                                               unsigned short* __restrict__ out_bf,
                                               float* __restrict__ out_f,
                                               int mode)
{
    __shared__ unsigned short Wl[128 * 128];   // 32 KB, XOR-swizzled [n][k]
    __shared__ unsigned short Al[32 * 128];    // 8 KB, XOR-swizzled [row][k] bf16
    const int t = threadIdx.x;
    const int w = t >> 6;
    const int lane = t & 63;
    const int grow0 = blockIdx.x * 32;
    const int colb = lane & 15;
    const int hi = lane >> 4;
    const int g = t >> 4;        // 16-lane group id = local row, 0..31
    const int l16 = t & 15;

    const int rt = w & 1;
    const int ct0 = w >> 1;                    // col-tiles ct0 and ct0+4
    const int arow = rt * 16 + colb;
    const int aswz = (arow & 7) << 4;

    // ---- phase 1: gather all 8 relations for row = grow0 + g ----
    float a[8][8];
    #pragma unroll
    for (int m = 0; m < 8; m++)
        #pragma unroll
        for (int j = 0; j < 8; j++) a[m][j] = 0.f;
    int cdeg[8];
    #pragma unroll
    for (int m = 0; m < 8; m++) cdeg[m] = 0;

    int row = grow0 + g;
    if (row < NN) {
        int s_[8], e_[8];
        #pragma unroll
        for (int m = 0; m < 8; m++) s_[m] = off[m * NN + row];
        #pragma unroll
        for (int m = 0; m < 8; m++) e_[m] = off[m * NN + row + 1];
        #pragma unroll
        for (int m = 0; m < 8; m++) {
            int s = s_[m];
            int c = e_[m] - s;
            cdeg[m] = c;
            int k = 0;
            for (; k + 2 <= c; k += 2) {
                int p0 = srt[s + k];
                int p1 = srt[s + k + 1];
                uint4 u0 = *(const uint4*)(Xin + (size_t)p0 * 128 + l16 * 8);
                uint4 u1 = *(const uint4*)(Xin + (size_t)p1 * 128 + l16 * 8);
                a[m][0] += bflo(u0.x) + bflo(u1.x); a[m][1] += bfhi(u0.x) + bfhi(u1.x);
                a[m][2] += bflo(u0.y) + bflo(u1.y); a[m][3] += bfhi(u0.y) + bfhi(u1.y);
                a[m][4] += bflo(u0.z) + bflo(u1.z); a[m][5] += bfhi(u0.z) + bfhi(u1.z);
                a[m][6] += bflo(u0.w) + bflo(u1.w); a[m][7] += bfhi(u0.w) + bfhi(u1.w);
            }
            if (k < c) {
                int p0 = srt[s + k];
                uint4 u0 = *(const uint4*)(Xin + (size_t)p0 * 128 + l16 * 8);
                a[m][0] += bflo(u0.x); a[m][1] += bfhi(u0.x);
                a[m][2] += bflo(u0.y); a[m][3] += bfhi(u0.y);
                a[m][4] += bflo(u0.z); a[m][5] += bfhi(u0.z);
                a[m][6] += bflo(u0.w); a[m][7] += bfhi(u0.w);
            }
        }
    }

    f32x4 acc[2];
    acc[0] = f32x4{0.f, 0.f, 0.f, 0.f};
    acc[1] = f32x4{0.f, 0.f, 0.f, 0.f};

    // ---- phase 2: per matrix m ----
    #pragma unroll
    for (int m = 0; m < 9; m++) {
        // stage W_m (transposed [n][k]) into Wl with swizzle
        {
            const uint4* wsrc = (const uint4*)(Wb + (size_t)m * 16384);
            #pragma unroll
            for (int c = 0; c < 4; c++) {
                int u = c * 512 + t;           // 16B chunk id, 0..2047
                uint4 v = wsrc[u];
                int n = u >> 4;
                int dstb = (u * 16) ^ ((n & 7) << 4);
                *(uint4*)((char*)Wl + dstb) = v;
            }
        }
        // dump A_m from registers (scaled by 1/cnt) into Al
        if (m < 8) {
            float invc = 1.0f / (float)(cdeg[m] > 1 ? cdeg[m] : 1);
            uint4 o;
            o.x = (unsigned int)f2bf(a[m][0] * invc) | ((unsigned int)f2bf(a[m][1] * invc) << 16);
            o.y = (unsigned int)f2bf(a[m][2] * invc) | ((unsigned int)f2bf(a[m][3] * invc) << 16);
            o.z = (unsigned int)f2bf(a[m][4] * invc) | ((unsigned int)f2bf(a[m][5] * invc) << 16);
            o.w = (unsigned int)f2bf(a[m][6] * invc) | ((unsigned int)f2bf(a[m][7] * invc) << 16);
            int byteoff = (g * 256 + l16 * 16) ^ ((g & 7) << 4);
            *(uint4*)((char*)Al + byteoff) = o;
        }
        __syncthreads();

        if (m < 8) {
            #pragma unroll
            for (int ks = 0; ks < 4; ks++) {
                int abyte = (arow * 256 + ks * 64 + hi * 16) ^ aswz;
                short8 af = *(const short8*)((const char*)Al + abyte);
                #pragma unroll
                for (int tti = 0; tti < 2; tti++) {
                    int n = (ct0 + tti * 4) * 16 + colb;
                    int bbyte = (n * 256 + ks * 64 + hi * 16) ^ ((n & 7) << 4);
                    short8 bfr = *(const short8*)((const char*)Wl + bbyte);
                    acc[tti] = __builtin_amdgcn_mfma_f32_16x16x32_bf16(af, bfr, acc[tti], 0, 0, 0);
                }
            }
        } else {
            // root term: A-fragments straight from global Xin
            int rowg = grow0 + arow;
            #pragma unroll
            for (int ks = 0; ks < 4; ks++) {
                short8 af = short8{0,0,0,0,0,0,0,0};
                if (rowg < NN)
                    af = *(const short8*)(Xin + (size_t)rowg * 128 + ks * 32 + hi * 8);
                #pragma unroll
                for (int tti = 0; tti < 2; tti++) {
                    int n = (ct0 + tti * 4) * 16 + colb;
                    int bbyte = (n * 256 + ks * 64 + hi * 16) ^ ((n & 7) << 4);
                    short8 bfr = *(const short8*)((const char*)Wl + bbyte);
                    acc[tti] = __builtin_amdgcn_mfma_f32_16x16x32_bf16(af, bfr, acc[tti], 0, 0, 0);
                }
            }
        }
        __syncthreads();
    }

    // ---- epilogue ----
    if (mode == 0) {
        #pragma unroll
        for (int tti = 0; tti < 2; tti++) {
            int col = (ct0 + tti * 4) * 16 + colb;
            float bc = bias[col];
            #pragma unroll
            for (int j = 0; j < 4; j++) {
                int rowg = grow0 + rt * 16 + hi * 4 + j;
                if (rowg < NN) {
                    float v = fmaxf(acc[tti][j] + bc, 0.f);
                    out_bf[(size_t)rowg * 128 + col] = f2bf(v);
                }
            }
        }
    } else {
        float vv[2][4];
        float ss[4] = {0.f, 0.f, 0.f, 0.f};
        #pragma unroll
        for (int tti = 0; tti < 2; tti++) {
            int col = (ct0 + tti * 4) * 16 + colb;
            float bc = bias[col];
            #pragma unroll
            for (int j = 0; j < 4; j++) {
                float v = acc[tti][j] + bc;
                vv[tti][j] = v;
                ss[j] += v * v;
            }
        }
        #pragma unroll
        for (int j = 0; j < 4; j++) {
            #pragma unroll
            for (int o = 1; o < 16; o <<= 1) ss[j] += __shfl_xor(ss[j], o);
        }
        float* nrm = (float*)Al;   // [32][4] partials
        if (colb == 0) {
            #pragma unroll
            for (int j = 0; j < 4; j++) nrm[(rt * 16 + hi * 4 + j) * 4 + ct0] = ss[j];
        }
        __syncthreads();
        #pragma unroll
        for (int tti = 0; tti < 2; tti++) {
            int col = (ct0 + tti * 4) * 16 + colb;
            #pragma unroll
            for (int j = 0; j < 4; j++) {
                int rl = rt * 16 + hi * 4 + j;
                int rowg = grow0 + rl;
                if (rowg < NN) {
                    float tot = nrm[rl * 4] + nrm[rl * 4 + 1] + nrm[rl * 4 + 2] + nrm[rl * 4 + 3];
                    float inv = 1.0f / fmaxf(sqrtf(tot), 1e-12f);
                    out_f[(size_t)rowg * 128 + col] = vv[tti][j] * inv;
                }
            }
        }
    }
}

extern "C" void kernel_launch(void* const* d_in, const int* in_sizes, int n_in,
                              void* d_out, int out_size, void* d_ws, size_t ws_size,
                              hipStream_t stream)
{
    const float* x     = (const float*)d_in[0];
    const int*   ei    = (const int*)d_in[1];   // [2, E]
    const int*   et    = (const int*)d_in[2];   // [E]
    const float* W1    = (const float*)d_in[3];
    const float* root1 = (const float*)d_in[4];
    const float* b1    = (const float*)d_in[5];
    const float* W2    = (const float*)d_in[6];
    const float* root2 = (const float*)d_in[7];
    const float* b2    = (const float*)d_in[8];
    float* out = (float*)d_out;

    char* ws = (char*)d_ws;
    int* cnt   = (int*)ws;                       // MB
    int* fill  = cnt + MB;                       // MB (adjacent for one memset)
    int* off   = fill + MB;                      // MB+1
    int* bsum  = off + MB + 1;                   // 256
    int* carry = bsum + 256;                     // 256
    int* srt   = carry + 256;                    // NE
    unsigned short* Xb = (unsigned short*)(srt + NE);       // NN*128
    unsigned short* hb = Xb + (size_t)NN * DD;              // NN*128
    unsigned short* Wb = hb + (size_t)NN * DD;              // 18*16384

    hipMemsetAsync(cnt, 0, (size_t)2 * MB * 4, stream);

    k_count<<<(NE + 255) / 256, 256, 0, stream>>>(ei, et, cnt);
    k_scan1<<<NBLK, 256, 0, stream>>>(cnt, off, bsum);
    k_scan2<<<1, 256, 0, stream>>>(bsum, carry);
    k_scan3<<<NBLK, 256, 0, stream>>>(off, carry);
    k_place<<<(NE + 255) / 256, 256, 0, stream>>>(ei, et, off, fill, srt);

    k_tobf16<<<(NN * DD / 4 + 255) / 256, 256, 0, stream>>>(x, Xb, NN * DD / 4);
    k_wconv<<<(18 * 16384 + 255) / 256, 256, 0, stream>>>(W1, root1, W2, root2, Wb);

    int lay_grid = (NN + 31) / 32;   // 1563
    k_layer<<<lay_grid, 512, 0, stream>>>(Xb, Wb, b1, off, srt, hb, nullptr, 0);
    k_layer<<<lay_grid, 512, 0, stream>>>(hb, Wb + (size_t)9 * 16384, b2, off, srt, nullptr, out, 1);
}